// Round 1
// baseline (939.755 us; speedup 1.0000x reference)
//
#include <hip/hip_runtime.h>

#define BN 64
#define SN 128
#define TN 64
#define FN 100
#define G3 300

__device__ __forceinline__ float rl(float v, int l){
  return __int_as_float(__builtin_amdgcn_readlane(__float_as_int(v), l));
}
__device__ __forceinline__ float fast_exp(float x){        // e^x
  return __builtin_amdgcn_exp2f(x * 1.44269504088896341f);
}
__device__ __forceinline__ float fast_tanh(float x){
  float e = __builtin_amdgcn_exp2f(x * 2.88539008177792681f);
  return 1.0f - 2.0f * __builtin_amdgcn_rcpf(1.0f + e);
}
__device__ __forceinline__ float fast_sig(float x){
  return __builtin_amdgcn_rcpf(1.0f + __builtin_amdgcn_exp2f(-1.44269504088896341f * x));
}

// ---------------------------------------------------------------------------
// Kernel 1: xw[row][o] = sum_f x[row][f] * W[f][o] + b[o]   (rows = B*S*T)
// W accessed with wave-uniform indices -> scalarized to s_load; 10k FMA/thread.
// ---------------------------------------------------------------------------
__global__ __launch_bounds__(256, 3) void k_xw(
    const float* __restrict__ x, const float* __restrict__ W,
    const float* __restrict__ b, float* __restrict__ xw)
{
  const long row = (long)blockIdx.x * 256 + threadIdx.x;
  const float4* xr4 = reinterpret_cast<const float4*>(x + row * FN);
  float acc[FN];
  #pragma unroll
  for (int j = 0; j < FN; j++) acc[j] = b[j];
  #pragma unroll 1
  for (int fc = 0; fc < 25; fc++){
    float4 xv = xr4[fc];
    const float* Wr = W + fc * 4 * FN;
    #pragma unroll
    for (int j = 0; j < FN; j++) acc[j] = fmaf(xv.x, Wr[j],        acc[j]);
    #pragma unroll
    for (int j = 0; j < FN; j++) acc[j] = fmaf(xv.y, Wr[FN + j],   acc[j]);
    #pragma unroll
    for (int j = 0; j < FN; j++) acc[j] = fmaf(xv.z, Wr[2*FN + j], acc[j]);
    #pragma unroll
    for (int j = 0; j < FN; j++) acc[j] = fmaf(xv.w, Wr[3*FN + j], acc[j]);
  }
  float4* op = reinterpret_cast<float4*>(xw + row * FN);
  #pragma unroll
  for (int j = 0; j < 25; j++)
    op[j] = make_float4(acc[4*j], acc[4*j+1], acc[4*j+2], acc[4*j+3]);
}

// ---------------------------------------------------------------------------
// Kernel 2: per-batch sequential scan. One block (512 thr, 8 waves) per batch.
// ---------------------------------------------------------------------------
__global__ __launch_bounds__(512, 2) void k_scan(
    const float* __restrict__ x, const float* __restrict__ xw,
    const float* __restrict__ Wc, const float* __restrict__ u,
    const float* __restrict__ Wx, const float* __restrict__ Wh,
    const float* __restrict__ bg, float* __restrict__ out)
{
  const int b    = blockIdx.x;
  const int tid  = threadIdx.x;
  const int lane = tid & 63;
  const int wid  = tid >> 6;

  // phase A/D layout: 4 f-slices of 25  x 128 "g-threads"
  const int gth = tid & 127;
  const int fsl = tid >> 7;
  // phase B layout: 64 t x 8 f-slices of 14
  const int tB  = tid >> 3;
  const int fsB = tid & 7;
  // phase C layout: f x 4 t-slices of 16
  const bool fCv = (tid & 127) < FN;
  const int fC  = fCv ? (tid & 127) : (FN - 1);
  const int tsC = tid >> 7;

  __shared__ __align__(16) float xwbuf[2][TN*FN + 16];   // +16 pad for tail-slice overreads
  __shared__ float part5[700][5];   // rows 0..599: gate partials; 600..699: c / attended partials
  __shared__ float h_lds[128];
  __shared__ __align__(16) float c_lds[128];
  __shared__ float att_lds[128];
  __shared__ __align__(16) float ea_lds[64];
  __shared__ float dpart[8];

  // ---- per-thread weight registers ----
  // outputs o = gth + 128*p, p<5; o<300 -> gx (Wx), 300<=o<600 -> gh (Wh)
  float wr[25][5];
  float wcr[25];
  const bool hasC = (gth >= 28);
  const int  co   = hasC ? gth - 28 : 0;
  #pragma unroll
  for (int j = 0; j < 25; j++){
    const int f = fsl*25 + j;
    #pragma unroll
    for (int p = 0; p < 5; p++){
      const int o = gth + 128*p;
      wr[j][p] = (o < 600) ? ((o < 300) ? Wx[f*G3 + o] : Wh[f*G3 + (o-300)]) : 0.0f;
    }
    wcr[j] = hasC ? Wc[f*FN + co] : 0.0f;
  }
  // u slices for phase B (zero-padded past f=99)
  float2 ur[7];
  #pragma unroll
  for (int i = 0; i < 7; i++){
    const int f = fsB*14 + 2*i;
    ur[i].x = (f   < FN) ? u[f]   : 0.0f;
    ur[i].y = (f+1 < FN) ? u[f+1] : 0.0f;
  }
  // init LDS (h=0; zero pads so garbage never becomes NaN through tanh)
  if (tid < 128){ h_lds[tid] = 0.0f; c_lds[tid] = 0.0f; att_lds[tid] = 0.0f; }
  if (tid < 16){ xwbuf[0][TN*FN + tid] = 0.0f; xwbuf[1][TN*FN + tid] = 0.0f; }
  __syncthreads();

  const long tileStride = (long)TN*FN;                 // 6400
  const float* xw_base = xw + (long)b*SN*tileStride;
  const float* x_base  = x  + (long)b*SN*tileStride;

  auto issue_xw_dma = [&](int s, int bi){
    const char* g = (const char*)(xw_base + (long)s*tileStride);
    char* l = (char*)(&xwbuf[bi][0]);
    #pragma unroll
    for (int r = 0; r < 4; r++){
      const int chunk = (r*8 + wid) * 1024;
      if (chunk < 25600){
        __builtin_amdgcn_global_load_lds(
          (const __attribute__((address_space(1))) unsigned int*)(g + chunk + lane*16),
          (__attribute__((address_space(3))) unsigned int*)(l + chunk),
          16, 0, 0);
      }
    }
  };

#define ISSUE_X(sp, arr) do { \
    const float* gp_ = x_base + (long)(sp)*tileStride + (long)tsC*(16*FN) + fC; \
    _Pragma("unroll") \
    for (int k_ = 0; k_ < 16; k_++) arr[k_] = gp_[k_*FN]; \
  } while(0)

  float xcur[16], xnxt[16];
  issue_xw_dma(0, 0);
  ISSUE_X(0, xcur);

  for (int s = 0; s < SN; s++){
    // ---- phase A: c = h @ Wc ----
    float hp = h_lds[fsl*25 + (lane < 25 ? lane : 0)];  // old h, packed for readlane
    float accC = 0.0f;
    #pragma unroll
    for (int j = 0; j < 25; j++) accC = fmaf(rl(hp, j), wcr[j], accC);
    if (hasC) part5[600 + co][fsl] = accC;
    __syncthreads();                                    // bar1

    if (tid < FN)
      c_lds[tid] = part5[600+tid][0] + part5[600+tid][1]
                 + part5[600+tid][2] + part5[600+tid][3];
    __syncthreads();                                    // bar2

    // ---- phase B: ait[t] = sum_f u[f]*tanh(xw + c), ea = exp(ait) ----
    {
      const float2* cp  = reinterpret_cast<const float2*>(&c_lds[fsB*14]);
      const float2* xp2 = reinterpret_cast<const float2*>(&xwbuf[s&1][tB*FN + fsB*14]);
      float accB = 0.0f;
      #pragma unroll
      for (int i = 0; i < 7; i++){
        float2 cc = cp[i];
        float2 xx = xp2[i];
        accB = fmaf(fast_tanh(xx.x + cc.x), ur[i].x, accB);
        accB = fmaf(fast_tanh(xx.y + cc.y), ur[i].y, accB);
      }
      accB += __shfl_xor(accB, 1);
      accB += __shfl_xor(accB, 2);
      accB += __shfl_xor(accB, 4);
      float ea = fast_exp(accB);
      if (fsB == 0) ea_lds[tB] = ea;
      float dsum = ea;                                  // wave-level denom partial
      dsum += __shfl_xor(dsum, 8);
      dsum += __shfl_xor(dsum, 16);
      dsum += __shfl_xor(dsum, 32);
      if (lane == 0) dpart[wid] = dsum;
    }
    __syncthreads();                                    // bar3

    // ---- phase C: attended partials (unnormalized) ----
    {
      const float4* eap = reinterpret_cast<const float4*>(&ea_lds[tsC*16]);
      float4 e0 = eap[0], e1 = eap[1], e2 = eap[2], e3 = eap[3];
      float a = 0.0f;
      a = fmaf(xcur[0],  e0.x, a); a = fmaf(xcur[1],  e0.y, a);
      a = fmaf(xcur[2],  e0.z, a); a = fmaf(xcur[3],  e0.w, a);
      a = fmaf(xcur[4],  e1.x, a); a = fmaf(xcur[5],  e1.y, a);
      a = fmaf(xcur[6],  e1.z, a); a = fmaf(xcur[7],  e1.w, a);
      a = fmaf(xcur[8],  e2.x, a); a = fmaf(xcur[9],  e2.y, a);
      a = fmaf(xcur[10], e2.z, a); a = fmaf(xcur[11], e2.w, a);
      a = fmaf(xcur[12], e3.x, a); a = fmaf(xcur[13], e3.y, a);
      a = fmaf(xcur[14], e3.z, a); a = fmaf(xcur[15], e3.w, a);
      if (fCv) part5[600 + fC][tsC] = a;                // overlay (c partials are dead)
    }
    __syncthreads();                                    // bar4

    if (tid < FN){
      float den = dpart[0]+dpart[1]+dpart[2]+dpart[3]
                + dpart[4]+dpart[5]+dpart[6]+dpart[7] + 1e-7f;
      float sm = part5[600+tid][0]+part5[600+tid][1]
               + part5[600+tid][2]+part5[600+tid][3];
      att_lds[tid] = sm / den;
    }
    __syncthreads();                                    // bar5

    // ---- prefetch next tiles (long phase D below hides the latency) ----
    {
      const int sp = (s+1 < SN) ? s+1 : s;
      issue_xw_dma(sp, (s+1)&1);
      ISSUE_X(sp, xnxt);
    }

    // ---- phase D: gx = att@Wx, gh = h@Wh (register weights + readlane) ----
    {
      float attp = att_lds[fsl*25 + (lane < 25 ? lane : 0)];
      const bool p2x = (gth < 44);                      // p=2 output is gx iff gth<44
      float a0=0.f, a1=0.f, a2=0.f, a3=0.f, a4=0.f;
      #pragma unroll
      for (int j = 0; j < 25; j++){
        float sa = rl(attp, j);
        float sh = rl(hp, j);
        float s2 = p2x ? sa : sh;
        a0 = fmaf(sa, wr[j][0], a0);
        a1 = fmaf(sa, wr[j][1], a1);
        a2 = fmaf(s2, wr[j][2], a2);
        a3 = fmaf(sh, wr[j][3], a3);
        a4 = fmaf(sh, wr[j][4], a4);
      }
      part5[gth      ][fsl] = a0;
      part5[gth + 128][fsl] = a1;
      part5[gth + 256][fsl] = a2;
      part5[gth + 384][fsl] = a3;
      if (gth < 88) part5[gth + 512][fsl] = a4;
    }
    __builtin_amdgcn_s_waitcnt(0x0F70);                 // vmcnt(0): DMA definitely in LDS
    __syncthreads();                                    // bar6

    // ---- GRU update ----
    if (tid < FN){
      const int g = tid;
      float gxz = part5[g    ][0]+part5[g    ][1]+part5[g    ][2]+part5[g    ][3] + bg[g];
      float gxr = part5[100+g][0]+part5[100+g][1]+part5[100+g][2]+part5[100+g][3] + bg[100+g];
      float gxh = part5[200+g][0]+part5[200+g][1]+part5[200+g][2]+part5[200+g][3] + bg[200+g];
      float ghz = part5[300+g][0]+part5[300+g][1]+part5[300+g][2]+part5[300+g][3];
      float ghr = part5[400+g][0]+part5[400+g][1]+part5[400+g][2]+part5[400+g][3];
      float ghh = part5[500+g][0]+part5[500+g][1]+part5[500+g][2]+part5[500+g][3];
      float z  = fast_sig(gxz + ghz);
      float r  = fast_sig(gxr + ghr);
      float ht = fast_tanh(gxh + r*ghh);
      float hn = (1.0f - z)*h_lds[g] + z*ht;
      h_lds[g] = hn;
      out[((long)b*SN + s)*FN + g] = hn;
    }
    __syncthreads();                                    // bar7
    #pragma unroll
    for (int k = 0; k < 16; k++) xcur[k] = xnxt[k];
  }
#undef ISSUE_X
}

extern "C" void kernel_launch(void* const* d_in, const int* in_sizes, int n_in,
                              void* d_out, int out_size, void* d_ws, size_t ws_size,
                              hipStream_t stream)
{
  const float* x  = (const float*)d_in[0];
  const float* W  = (const float*)d_in[1];
  const float* Wc = (const float*)d_in[2];
  const float* bb = (const float*)d_in[3];
  const float* u  = (const float*)d_in[4];
  const float* Wx = (const float*)d_in[5];
  const float* Wh = (const float*)d_in[6];
  const float* bg = (const float*)d_in[7];
  float* out = (float*)d_out;
  float* xwbuf = (float*)d_ws;   // needs B*S*T*F*4 = 209,715,200 bytes

  k_xw  <<<dim3((BN*SN*TN) / 256 * 1), dim3(256), 0, stream>>>(x, W, bb, xwbuf);
  k_scan<<<dim3(BN), dim3(512), 0, stream>>>(x, xwbuf, Wc, u, Wx, Wh, bg, out);
}